// Round 6
// baseline (413.899 us; speedup 1.0000x reference)
//
#include <hip/hip_runtime.h>

// ---------------------------------------------------------------------------
// GIN 2-layer forward (bf16 features, MFMA GEMMs, CSR gather segment-sum):
//   CSR bucket edges by dst (hist -> parallel scan -> fill)
//   p1 = bf16( x @ w1a )                      [b1a cancels in BN]
//   s1 = bf16( p1[n] + gather-sum )           (fused column stats)
//   h1 = bf16( relu( relu(sc1*s1+sh1) @ w1b + b1b ) )
//   p2 = bf16( h1 @ w2a )                     [b2a cancels in BN]
//   s2 = bf16( p2[n] + gather-sum )           (fused stats)
//   out = log_softmax( relu(sc2*s2+sh2) @ w2b + b2b )  fp32, fused epilogue
// segsum: wave-per-node; 64 indices per vector load; readlane->SGPR index
// broadcast; 8 independent named gather dests per clump (forced MLP).
// ---------------------------------------------------------------------------

typedef unsigned short u16;
typedef unsigned int u32;
typedef __attribute__((ext_vector_type(8))) short short8;
typedef __attribute__((ext_vector_type(4))) short short4v;
typedef __attribute__((ext_vector_type(4))) float f32x4;

#define DEV_INLINE __device__ __forceinline__

DEV_INLINE void atomAddF(float* p, float v) { unsafeAtomicAdd(p, v); }

DEV_INLINE u16 f2bf(float f) {
    unsigned u = __float_as_uint(f);
    u += 0x7fffu + ((u >> 16) & 1u);   // round-to-nearest-even
    return (u16)(u >> 16);
}
DEV_INLINE float bf2f(u16 h) { return __uint_as_float(((unsigned)h) << 16); }

// ---------------------------------------------------------------------------
// Weight prep (all 4 weights, one launch): W[K][NOUT] fp32 -> frag-ordered
// bf16 (MFMA A-operand, swapped). unit=(ct,kc,lane): 8 bf16 for
// col=ct*16+(lane&15), k=kc*32+(lane>>4)*8+j.
// ---------------------------------------------------------------------------
__global__ __launch_bounds__(256) void wprep4_k(
    const float* __restrict__ w1a, const float* __restrict__ w1b,
    const float* __restrict__ w2a, const float* __restrict__ w2b,
    short* __restrict__ o1a, short* __restrict__ o1b,
    short* __restrict__ o2a, short* __restrict__ o2b)
{
    int b = blockIdx.x;
    const float* W; short* wf; int K, NOUT;
    if (b < 8)       { W = w1a; wf = o1a; K = 128; NOUT = 128; }
    else if (b < 16) { W = w1b; wf = o1b; K = 128; NOUT = 128; b -= 8; }
    else if (b < 20) { W = w2a; wf = o2a; K = 128; NOUT = 64;  b -= 16; }
    else             { W = w2b; wf = o2b; K = 64;  NOUT = 64;  b -= 20; }
    const int u = b * 256 + threadIdx.x;
    const int units = (NOUT / 16) * (K / 32) * 64;
    if (u >= units) return;
    const int per_ct = (K / 32) * 64;
    const int ct = u / per_ct;
    const int rem = u % per_ct;
    const int kc = rem >> 6;
    const int l = rem & 63;
    const int col = ct * 16 + (l & 15);
    const int k0 = kc * 32 + (l >> 4) * 8;
    short8 pk;
#pragma unroll
    for (int j = 0; j < 8; j++)
        pk[j] = (short)f2bf(W[(size_t)(k0 + j) * NOUT + col]);
    *(short8*)&wf[(size_t)u * 8] = pk;
}

// ---------------------------------------------------------------------------
// MFMA GEMM (swapped operands => per-lane contiguous C-writes):
//   out[M][NC] = f(A[M][KD]) @ W  (+bias) (+relu | +row log_softmax)
// A is fp32 or bf16; out is bf16 or fp32. BM=128 rows, 256 threads (4 waves).
// ---------------------------------------------------------------------------
template <int KD, int NC, bool ABF16, bool BNIN, bool BIAS, bool RELUOUT,
          bool LOGSM, bool OBF16>
__global__ __launch_bounds__(256) void mgemm(
    const void* __restrict__ Ap, const short* __restrict__ Wf,
    const float* __restrict__ sc, const float* __restrict__ sh,
    const float* __restrict__ bias, void* __restrict__ outp, int M)
{
    constexpr int BM = 128;
    constexpr int KC = KD / 32;   // 32-wide k chunks
    constexpr int CT = NC / 16;   // 16-wide col tiles
    __shared__ short Asl[BM * KD];
    __shared__ short Bsl[NC * KD];

    const int t = threadIdx.x;
    const int l = t & 63;
    const int w = t >> 6;

    // ---- stage B: frag-ordered weights, linear copy ----
    {
        const float4* src = (const float4*)Wf;
        float4* dst = (float4*)Bsl;
        constexpr int NU = NC * KD / 8;
#pragma unroll
        for (int u = t; u < NU; u += 256) dst[u] = src[u];
    }
    // ---- stage A: 2 threads per row -> (BN+ReLU) -> bf16 frags ----
    {
        const int r = t >> 1;
        const int half = t & 1;
        const int grow = blockIdx.x * BM + r;
        const int rt = r >> 4;
        constexpr int KH = KD / 2;
        u16 hv[KH];
        if (grow < M) {
            if constexpr (ABF16) {
                const u16* ap = (const u16*)Ap + (size_t)grow * KD + half * KH;
#pragma unroll
                for (int i = 0; i < KH / 8; i++)
                    *(short8*)&hv[i * 8] = ((const short8*)ap)[i];
                if constexpr (BNIN) {
#pragma unroll
                    for (int i = 0; i < KH; i++) {
                        const int k = half * KH + i;
                        hv[i] = f2bf(fmaxf(0.f, bf2f(hv[i]) * sc[k] + sh[k]));
                    }
                }
            } else {
                const float* ap = (const float*)Ap + (size_t)grow * KD + half * KH;
#pragma unroll
                for (int i = 0; i < KH / 4; i++) {
                    const float4 v = ((const float4*)ap)[i];
                    float f0 = v.x, f1 = v.y, f2 = v.z, f3 = v.w;
                    if constexpr (BNIN) {
                        const int k = half * KH + i * 4;
                        f0 = fmaxf(0.f, f0 * sc[k + 0] + sh[k + 0]);
                        f1 = fmaxf(0.f, f1 * sc[k + 1] + sh[k + 1]);
                        f2 = fmaxf(0.f, f2 * sc[k + 2] + sh[k + 2]);
                        f3 = fmaxf(0.f, f3 * sc[k + 3] + sh[k + 3]);
                    }
                    hv[i * 4 + 0] = f2bf(f0); hv[i * 4 + 1] = f2bf(f1);
                    hv[i * 4 + 2] = f2bf(f2); hv[i * 4 + 3] = f2bf(f3);
                }
            }
        } else {
#pragma unroll
            for (int i = 0; i < KH; i++) hv[i] = 0;
        }
#pragma unroll
        for (int g = 0; g < KH / 8; g++) {
            const int k0 = half * KH + g * 8;
            const int kc = k0 >> 5;
            const int lane = (r & 15) + ((k0 >> 3) & 3) * 16;
            *(short8*)&Asl[((rt * KC + kc) * 64 + lane) * 8] =
                *(short8*)&hv[g * 8];
        }
    }
    __syncthreads();

    // ---- MFMA: wave w owns row-tiles {2w, 2w+1} x all col-tiles ----
    const int rt0 = w * 2;
    f32x4 acc[2][CT];
#pragma unroll
    for (int i = 0; i < 2; i++)
#pragma unroll
        for (int c = 0; c < CT; c++) acc[i][c] = (f32x4){0.f, 0.f, 0.f, 0.f};

#pragma unroll
    for (int kc = 0; kc < KC; kc++) {
        const short8 x0 = *(const short8*)&Asl[((rt0 * KC + kc) * 64 + l) * 8];
        const short8 x1 = *(const short8*)&Asl[(((rt0 + 1) * KC + kc) * 64 + l) * 8];
#pragma unroll
        for (int ct = 0; ct < CT; ct++) {
            const short8 wb = *(const short8*)&Bsl[((ct * KC + kc) * 64 + l) * 8];
            acc[0][ct] = __builtin_amdgcn_mfma_f32_16x16x32_bf16(wb, x0, acc[0][ct], 0, 0, 0);
            acc[1][ct] = __builtin_amdgcn_mfma_f32_16x16x32_bf16(wb, x1, acc[1][ct], 0, 0, 0);
        }
    }

    // ---- epilogue: lane l holds row (l&15), cols (l>>4)*4+{0..3} of tile ----
    const int cbase = (l >> 4) * 4;
#pragma unroll
    for (int rr = 0; rr < 2; rr++) {
        const int grow = blockIdx.x * BM + (rt0 + rr) * 16 + (l & 15);
        if constexpr (!LOGSM) {
            if (grow < M) {
#pragma unroll
                for (int ct = 0; ct < CT; ct++) {
                    f32x4 o = acc[rr][ct];
                    if constexpr (BIAS) {
                        const float4 bv = *(const float4*)&bias[ct * 16 + cbase];
                        o[0] += bv.x; o[1] += bv.y; o[2] += bv.z; o[3] += bv.w;
                    }
                    if constexpr (RELUOUT) {
#pragma unroll
                        for (int j = 0; j < 4; j++) o[j] = fmaxf(o[j], 0.f);
                    }
                    if constexpr (OBF16) {
                        short4v o16;
#pragma unroll
                        for (int j = 0; j < 4; j++) o16[j] = (short)f2bf(o[j]);
                        *(short4v*)&((u16*)outp)[(size_t)grow * NC + ct * 16 + cbase] = o16;
                    } else {
                        *(f32x4*)&((float*)outp)[(size_t)grow * NC + ct * 16 + cbase] = o;
                    }
                }
            }
        } else {
            // fused row log_softmax (row spread across lanes l, l^16, l^32, l^48)
            float v[CT * 4];
#pragma unroll
            for (int ct = 0; ct < CT; ct++) {
                const float4 bv = *(const float4*)&bias[ct * 16 + cbase];
                v[ct * 4 + 0] = acc[rr][ct][0] + bv.x;
                v[ct * 4 + 1] = acc[rr][ct][1] + bv.y;
                v[ct * 4 + 2] = acc[rr][ct][2] + bv.z;
                v[ct * 4 + 3] = acc[rr][ct][3] + bv.w;
            }
            float m = v[0];
#pragma unroll
            for (int j = 1; j < CT * 4; j++) m = fmaxf(m, v[j]);
            m = fmaxf(m, __shfl_xor(m, 16));
            m = fmaxf(m, __shfl_xor(m, 32));
            float s = 0.f;
#pragma unroll
            for (int j = 0; j < CT * 4; j++) s += __expf(v[j] - m);
            s += __shfl_xor(s, 16);
            s += __shfl_xor(s, 32);
            const float lg = m + __logf(s);
            if (grow < M) {
#pragma unroll
                for (int ct = 0; ct < CT; ct++) {
                    f32x4 o;
#pragma unroll
                    for (int j = 0; j < 4; j++) o[j] = v[ct * 4 + j] - lg;
                    *(f32x4*)&((float*)outp)[(size_t)grow * NC + ct * 16 + cbase] = o;
                }
            }
        }
    }
}

// ---------------------------------------------------------------------------
// CSR build: histogram, 3-kernel parallel exclusive scan, bucket fill.
// ---------------------------------------------------------------------------
__global__ __launch_bounds__(256) void hist_k(const int* __restrict__ ei,
                                              int* __restrict__ cnt, int E)
{
    const int gid = blockIdx.x * blockDim.x + threadIdx.x;
    const int stride = gridDim.x * blockDim.x;
    for (int e = gid; e < E; e += stride) atomicAdd(&cnt[ei[E + e]], 1);
}

__global__ __launch_bounds__(256) void bsum_k(const int* __restrict__ cnt,
                                              int* __restrict__ bsum, int N)
{
    __shared__ int ws[4];
    const int i = blockIdx.x * 256 + threadIdx.x;
    int v = (i < N) ? cnt[i] : 0;
    for (int d = 32; d; d >>= 1) v += __shfl_xor(v, d, 64);
    if ((threadIdx.x & 63) == 0) ws[threadIdx.x >> 6] = v;
    __syncthreads();
    if (threadIdx.x == 0) bsum[blockIdx.x] = ws[0] + ws[1] + ws[2] + ws[3];
}

// single block; G1 <= 256
__global__ __launch_bounds__(256) void bscan_k(const int* __restrict__ bsum,
                                               int* __restrict__ bpre, int G1)
{
    __shared__ int part[256];
    const int t = threadIdx.x;
    const int v = (t < G1) ? bsum[t] : 0;
    part[t] = v;
    __syncthreads();
    for (int d = 1; d < 256; d <<= 1) {
        const int u = (t >= d) ? part[t - d] : 0;
        __syncthreads();
        part[t] += u;
        __syncthreads();
    }
    bpre[t] = part[t] - v;   // exclusive
}

__global__ __launch_bounds__(256) void offs_k(const int* __restrict__ cnt,
                                              const int* __restrict__ bpre,
                                              int* __restrict__ off,
                                              int* __restrict__ cursor,
                                              int N, int E)
{
    __shared__ int part[256];
    const int t = threadIdx.x;
    const int i = blockIdx.x * 256 + t;
    const int v = (i < N) ? cnt[i] : 0;
    part[t] = v;
    __syncthreads();
    for (int d = 1; d < 256; d <<= 1) {
        const int u = (t >= d) ? part[t - d] : 0;
        __syncthreads();
        part[t] += u;
        __syncthreads();
    }
    if (i < N) {
        const int o = bpre[blockIdx.x] + part[t] - v;
        off[i] = o;
        cursor[i] = o;
    }
    if (blockIdx.x == 0 && t == 0) off[N] = E;
}

__global__ __launch_bounds__(256) void fill_k(const int* __restrict__ ei,
                                              int* __restrict__ cursor,
                                              int* __restrict__ srcs, int E)
{
    const int gid = blockIdx.x * blockDim.x + threadIdx.x;
    const int stride = gridDim.x * blockDim.x;
    for (int e = gid; e < E; e += stride) {
        const int s = ei[e];
        const int d = ei[E + e];
        const int pos = atomicAdd(&cursor[d], 1);
        srcs[pos] = s;
    }
}

// ---------------------------------------------------------------------------
// Gather 8 edges (one clump): indices come from lanes [g*8, g*8+8) of iv via
// v_readlane (SGPR broadcast); 8 loads into 8 named regs BEFORE any add.
// m = live count (uniform); m==8 for full clumps (folds at compile time).
// ---------------------------------------------------------------------------
template <int C, int VPL>
DEV_INLINE void gath8(const u16* __restrict__ p, int iv, int g, int l, int m,
                      float acc[VPL])
{
    u32 u[8];
#pragma unroll
    for (int j = 0; j < 8; j++) {
        const int s = __builtin_amdgcn_readlane(iv, g * 8 + j);
        if constexpr (VPL == 2)
            u[j] = *(const u32*)&p[(size_t)s * C + 2 * l];
        else
            u[j] = p[(size_t)s * C + l];
    }
#pragma unroll
    for (int j = 0; j < 8; j++) {
        if (j < m) {   // wave-uniform; constant-folds for full clumps
            acc[0] += bf2f((u16)u[j]);
            if constexpr (VPL == 2) acc[1] += bf2f((u16)(u[j] >> 16));
        }
    }
}

// ---------------------------------------------------------------------------
// Gather segment-sum (bf16 in/out) + fused column stats.
// One WAVE per node; 64 edge indices per vector load; 8-deep gather clumps.
// C=128 -> lane carries 2 channels (dword); C=64 -> lane = channel (ushort).
// ---------------------------------------------------------------------------
template <int C>
__global__ __launch_bounds__(256, 4) void segsum_bf(
    const u16* __restrict__ p, const int* __restrict__ off,
    const int* __restrict__ srcs, u16* __restrict__ out,
    float* __restrict__ sum, float* __restrict__ sumsq, int N)
{
    constexpr int BLKN = 4;            // nodes per wave
    constexpr int VPL = C / 64;        // channels per lane (2 or 1)
    __shared__ float red[4][64][2 * VPL];

    const int wv = threadIdx.x >> 6;
    const int l  = threadIdx.x & 63;
    const int base = blockIdx.x * 4 * BLKN;

    float ss[VPL], qq[VPL];
#pragma unroll
    for (int v = 0; v < VPL; v++) { ss[v] = 0.f; qq[v] = 0.f; }

    for (int i = 0; i < BLKN; i++) {
        const int n = base + i * 4 + wv;   // wave-uniform
        if (n < N) {
            const int lo = __builtin_amdgcn_readfirstlane(off[n]);
            const int hi = __builtin_amdgcn_readfirstlane(off[n + 1]);
            float acc[VPL];
            if constexpr (VPL == 2) {
                const u32 u = *(const u32*)&p[(size_t)n * C + 2 * l];
                acc[0] = bf2f((u16)u);
                acc[1] = bf2f((u16)(u >> 16));
            } else {
                acc[0] = bf2f(p[(size_t)n * C + l]);
            }
            int e = lo;
            // full 64-edge chunks: 1 index load + 8 clumps of 8
            for (; e + 64 <= hi; e += 64) {
                const int iv = srcs[e + l];
#pragma unroll
                for (int g = 0; g < 8; g++)
                    gath8<C, VPL>(p, iv, g, l, 8, acc);
            }
            // remainder (< 64 edges), clamped index load, guarded adds
            if (e < hi) {
                const int rem = hi - e;   // 1..63
                const int iv = srcs[min(e + l, hi - 1)];
#pragma unroll
                for (int g = 0; g < 8; g++) {
                    if (g * 8 < rem)
                        gath8<C, VPL>(p, iv, g, l, min(rem - g * 8, 8), acc);
                }
            }
            // store rounded + stats on the rounded values
            if constexpr (VPL == 2) {
                const u16 r0 = f2bf(acc[0]);
                const u16 r1 = f2bf(acc[1]);
                *(u32*)&out[(size_t)n * C + 2 * l] = (u32)r0 | ((u32)r1 << 16);
                const float f0 = bf2f(r0), f1 = bf2f(r1);
                ss[0] += f0; qq[0] += f0 * f0;
                ss[1] += f1; qq[1] += f1 * f1;
            } else {
                const u16 r = f2bf(acc[0]);
                out[(size_t)n * C + l] = r;
                const float f = bf2f(r);
                ss[0] += f; qq[0] += f * f;
            }
        }
    }

    // block reduce across the 4 waves, one atomic per channel per block
#pragma unroll
    for (int v = 0; v < VPL; v++) {
        red[wv][l][2 * v] = ss[v];
        red[wv][l][2 * v + 1] = qq[v];
    }
    __syncthreads();
    if (wv == 0) {
#pragma unroll
        for (int v = 0; v < VPL; v++) {
            float a = 0.f, b = 0.f;
#pragma unroll
            for (int w2 = 0; w2 < 4; w2++) {
                a += red[w2][l][2 * v];
                b += red[w2][l][2 * v + 1];
            }
            const int ch = (VPL == 2) ? (2 * l + v) : l;
            atomAddF(&sum[ch], a);
            atomAddF(&sumsq[ch], b);
        }
    }
}

__global__ void bnfinal_k(const float* __restrict__ sum,
                          const float* __restrict__ sumsq,
                          const float* __restrict__ g,
                          const float* __restrict__ be,
                          float* __restrict__ sc, float* __restrict__ sh,
                          int C, float invN)
{
    const int c = threadIdx.x;
    if (c < C) {
        const float m = sum[c] * invN;
        const float v = sumsq[c] * invN - m * m;
        const float r = rsqrtf(v + 1e-5f);
        const float s = g[c] * r;
        sc[c] = s;
        sh[c] = be[c] - m * s;
    }
}

extern "C" void kernel_launch(void* const* d_in, const int* in_sizes, int n_in,
                              void* d_out, int out_size, void* d_ws, size_t ws_size,
                              hipStream_t stream)
{
    const float* x   = (const float*)d_in[0];
    const int*   ei  = (const int*)d_in[1];
    const float* w1a = (const float*)d_in[2];
    // d_in[3] = b1a: cancelled by BN
    const float* g1  = (const float*)d_in[4];
    const float* be1 = (const float*)d_in[5];
    const float* w1b = (const float*)d_in[6];
    const float* b1b = (const float*)d_in[7];
    const float* w2a = (const float*)d_in[8];
    // d_in[9] = b2a: cancelled by BN
    const float* g2  = (const float*)d_in[10];
    const float* be2 = (const float*)d_in[11];
    const float* w2b = (const float*)d_in[12];
    const float* b2b = (const float*)d_in[13];
    float* out = (float*)d_out;

    const int N = in_sizes[0] / 128;   // 50000
    const int E = in_sizes[1] / 2;     // 800000

    // ---- workspace layout ----
    u16* buf1 = (u16*)d_ws;                      // N*128 bf16 : p1, then h1
    u16* buf2 = buf1 + (size_t)N * 128;          // N*128 bf16 : s1, then p2|s2
    float* stats = (float*)(buf2 + (size_t)N * 128);  // 1024 floats
    float* sum1 = stats,       *sq1 = stats + 128;
    float* sum2 = stats + 256, *sq2 = stats + 320;
    float* sc1  = stats + 384, *sh1 = stats + 512;
    float* sc2  = stats + 640, *sh2 = stats + 704;
    int* cnt    = (int*)(stats + 1024);          // N
    int* off    = cnt + N;                       // N+1
    int* cursor = off + N + 1;                   // N
    int* srcs   = cursor + N;                    // E
    int* bsum   = srcs + E;                      // 256
    int* bpre   = bsum + 256;                    // 256
    short* w1af = (short*)(bpre + 256);          // 128*128
    short* w1bf = w1af + 128 * 128;              // 128*128
    short* w2af = w1bf + 128 * 128;              // 128*64
    short* w2bf = w2af + 128 * 64;               // 64*64
    u16* p1 = buf1;
    u16* s1 = buf2;
    u16* h1 = buf1;                    // reuse: p1 dead after segsum1
    u16* p2 = buf2;                    // reuse: s1 dead after mgemm2 (N*64)
    u16* s2 = buf2 + (size_t)N * 64;   // upper half

    hipMemsetAsync(stats, 0, 1024 * sizeof(float) + (size_t)N * sizeof(int), stream);

    const int G1 = (N + 255) / 256;
    const int gb = (N + 127) / 128;
    const int gs = (N + 15) / 16;      // segsum: 4 waves x 4 nodes per block

    // ---- CSR build ----
    hist_k<<<1024, 256, 0, stream>>>(ei, cnt, E);
    bsum_k<<<G1, 256, 0, stream>>>(cnt, bsum, N);
    bscan_k<<<1, 256, 0, stream>>>(bsum, bpre, G1);
    offs_k<<<G1, 256, 0, stream>>>(cnt, bpre, off, cursor, N, E);
    fill_k<<<1024, 256, 0, stream>>>(ei, cursor, srcs, E);

    // ---- weight prep (one launch for all four) ----
    wprep4_k<<<22, 256, 0, stream>>>(w1a, w1b, w2a, w2b, w1af, w1bf, w2af, w2bf);

    // ---- Layer 1 ----
    mgemm<128, 128, false, false, false, false, false, true>
        <<<gb, 256, 0, stream>>>(x, w1af, nullptr, nullptr, nullptr, p1, N);
    segsum_bf<128><<<gs, 256, 0, stream>>>(p1, off, srcs, s1, sum1, sq1, N);
    bnfinal_k<<<1, 128, 0, stream>>>(sum1, sq1, g1, be1, sc1, sh1, 128, 1.f / N);
    mgemm<128, 128, true, true, true, true, false, true>
        <<<gb, 256, 0, stream>>>(s1, w1bf, sc1, sh1, b1b, h1, N);

    // ---- Layer 2 (aggregate after projecting to 64ch) ----
    mgemm<128, 64, true, false, false, false, false, true>
        <<<gb, 256, 0, stream>>>(h1, w2af, nullptr, nullptr, nullptr, p2, N);
    segsum_bf<64><<<gs, 256, 0, stream>>>(p2, off, srcs, s2, sum2, sq2, N);
    bnfinal_k<<<1, 64, 0, stream>>>(sum2, sq2, g2, be2, sc2, sh2, 64, 1.f / N);
    mgemm<64, 64, true, true, true, false, true, false>
        <<<gb, 256, 0, stream>>>(s2, w2bf, sc2, sh2, b2b, out, N);
}

// Round 7
// 411.909 us; speedup vs baseline: 1.0048x; 1.0048x over previous
//
#include <hip/hip_runtime.h>

// ---------------------------------------------------------------------------
// GIN 2-layer forward (bf16 features, MFMA GEMMs, CSR gather segment-sum):
//   CSR bucket edges by dst (hist -> parallel scan -> fill)
//   p1 = bf16( x @ w1a )                      [b1a cancels in BN]
//   s1 = bf16( p1[n] + gather-sum )           (fused column stats)
//   h1 = bf16( relu( relu(sc1*s1+sh1) @ w1b + b1b ) )
//   p2 = bf16( h1 @ w2a )                     [b2a cancels in BN]
//   s2 = bf16( p2[n] + gather-sum )           (fused stats)
//   out = log_softmax( relu(sc2*s2+sh2) @ w2b + b2b )  fp32, fused epilogue
// segsum: one wave per 4 nodes INTERLEAVED -> 8 structurally independent
// gathers in flight per wave (cross-node ILP, immune to per-node serial deps).
// ---------------------------------------------------------------------------

typedef unsigned short u16;
typedef unsigned int u32;
typedef __attribute__((ext_vector_type(8))) short short8;
typedef __attribute__((ext_vector_type(4))) short short4v;
typedef __attribute__((ext_vector_type(4))) float f32x4;

#define DEV_INLINE __device__ __forceinline__

DEV_INLINE void atomAddF(float* p, float v) { unsafeAtomicAdd(p, v); }

DEV_INLINE u16 f2bf(float f) {
    unsigned u = __float_as_uint(f);
    u += 0x7fffu + ((u >> 16) & 1u);   // round-to-nearest-even
    return (u16)(u >> 16);
}
DEV_INLINE float bf2f(u16 h) { return __uint_as_float(((unsigned)h) << 16); }

// ---------------------------------------------------------------------------
// Weight prep (all 4 weights, one launch): W[K][NOUT] fp32 -> frag-ordered
// bf16 (MFMA A-operand, swapped). unit=(ct,kc,lane): 8 bf16 for
// col=ct*16+(lane&15), k=kc*32+(lane>>4)*8+j.
// ---------------------------------------------------------------------------
__global__ __launch_bounds__(256) void wprep4_k(
    const float* __restrict__ w1a, const float* __restrict__ w1b,
    const float* __restrict__ w2a, const float* __restrict__ w2b,
    short* __restrict__ o1a, short* __restrict__ o1b,
    short* __restrict__ o2a, short* __restrict__ o2b)
{
    int b = blockIdx.x;
    const float* W; short* wf; int K, NOUT;
    if (b < 8)       { W = w1a; wf = o1a; K = 128; NOUT = 128; }
    else if (b < 16) { W = w1b; wf = o1b; K = 128; NOUT = 128; b -= 8; }
    else if (b < 20) { W = w2a; wf = o2a; K = 128; NOUT = 64;  b -= 16; }
    else             { W = w2b; wf = o2b; K = 64;  NOUT = 64;  b -= 20; }
    const int u = b * 256 + threadIdx.x;
    const int units = (NOUT / 16) * (K / 32) * 64;
    if (u >= units) return;
    const int per_ct = (K / 32) * 64;
    const int ct = u / per_ct;
    const int rem = u % per_ct;
    const int kc = rem >> 6;
    const int l = rem & 63;
    const int col = ct * 16 + (l & 15);
    const int k0 = kc * 32 + (l >> 4) * 8;
    short8 pk;
#pragma unroll
    for (int j = 0; j < 8; j++)
        pk[j] = (short)f2bf(W[(size_t)(k0 + j) * NOUT + col]);
    *(short8*)&wf[(size_t)u * 8] = pk;
}

// ---------------------------------------------------------------------------
// MFMA GEMM (swapped operands => per-lane contiguous C-writes):
//   out[M][NC] = f(A[M][KD]) @ W  (+bias) (+relu | +row log_softmax)
// A is fp32 or bf16; out is bf16 or fp32. BM=128 rows, 256 threads (4 waves).
// ---------------------------------------------------------------------------
template <int KD, int NC, bool ABF16, bool BNIN, bool BIAS, bool RELUOUT,
          bool LOGSM, bool OBF16>
__global__ __launch_bounds__(256) void mgemm(
    const void* __restrict__ Ap, const short* __restrict__ Wf,
    const float* __restrict__ sc, const float* __restrict__ sh,
    const float* __restrict__ bias, void* __restrict__ outp, int M)
{
    constexpr int BM = 128;
    constexpr int KC = KD / 32;   // 32-wide k chunks
    constexpr int CT = NC / 16;   // 16-wide col tiles
    __shared__ short Asl[BM * KD];
    __shared__ short Bsl[NC * KD];

    const int t = threadIdx.x;
    const int l = t & 63;
    const int w = t >> 6;

    // ---- stage B: frag-ordered weights, linear copy ----
    {
        const float4* src = (const float4*)Wf;
        float4* dst = (float4*)Bsl;
        constexpr int NU = NC * KD / 8;
#pragma unroll
        for (int u = t; u < NU; u += 256) dst[u] = src[u];
    }
    // ---- stage A: 2 threads per row -> (BN+ReLU) -> bf16 frags ----
    {
        const int r = t >> 1;
        const int half = t & 1;
        const int grow = blockIdx.x * BM + r;
        const int rt = r >> 4;
        constexpr int KH = KD / 2;
        u16 hv[KH];
        if (grow < M) {
            if constexpr (ABF16) {
                const u16* ap = (const u16*)Ap + (size_t)grow * KD + half * KH;
#pragma unroll
                for (int i = 0; i < KH / 8; i++)
                    *(short8*)&hv[i * 8] = ((const short8*)ap)[i];
                if constexpr (BNIN) {
#pragma unroll
                    for (int i = 0; i < KH; i++) {
                        const int k = half * KH + i;
                        hv[i] = f2bf(fmaxf(0.f, bf2f(hv[i]) * sc[k] + sh[k]));
                    }
                }
            } else {
                const float* ap = (const float*)Ap + (size_t)grow * KD + half * KH;
#pragma unroll
                for (int i = 0; i < KH / 4; i++) {
                    const float4 v = ((const float4*)ap)[i];
                    float f0 = v.x, f1 = v.y, f2 = v.z, f3 = v.w;
                    if constexpr (BNIN) {
                        const int k = half * KH + i * 4;
                        f0 = fmaxf(0.f, f0 * sc[k + 0] + sh[k + 0]);
                        f1 = fmaxf(0.f, f1 * sc[k + 1] + sh[k + 1]);
                        f2 = fmaxf(0.f, f2 * sc[k + 2] + sh[k + 2]);
                        f3 = fmaxf(0.f, f3 * sc[k + 3] + sh[k + 3]);
                    }
                    hv[i * 4 + 0] = f2bf(f0); hv[i * 4 + 1] = f2bf(f1);
                    hv[i * 4 + 2] = f2bf(f2); hv[i * 4 + 3] = f2bf(f3);
                }
            }
        } else {
#pragma unroll
            for (int i = 0; i < KH; i++) hv[i] = 0;
        }
#pragma unroll
        for (int g = 0; g < KH / 8; g++) {
            const int k0 = half * KH + g * 8;
            const int kc = k0 >> 5;
            const int lane = (r & 15) + ((k0 >> 3) & 3) * 16;
            *(short8*)&Asl[((rt * KC + kc) * 64 + lane) * 8] =
                *(short8*)&hv[g * 8];
        }
    }
    __syncthreads();

    // ---- MFMA: wave w owns row-tiles {2w, 2w+1} x all col-tiles ----
    const int rt0 = w * 2;
    f32x4 acc[2][CT];
#pragma unroll
    for (int i = 0; i < 2; i++)
#pragma unroll
        for (int c = 0; c < CT; c++) acc[i][c] = (f32x4){0.f, 0.f, 0.f, 0.f};

#pragma unroll
    for (int kc = 0; kc < KC; kc++) {
        const short8 x0 = *(const short8*)&Asl[((rt0 * KC + kc) * 64 + l) * 8];
        const short8 x1 = *(const short8*)&Asl[(((rt0 + 1) * KC + kc) * 64 + l) * 8];
#pragma unroll
        for (int ct = 0; ct < CT; ct++) {
            const short8 wb = *(const short8*)&Bsl[((ct * KC + kc) * 64 + l) * 8];
            acc[0][ct] = __builtin_amdgcn_mfma_f32_16x16x32_bf16(wb, x0, acc[0][ct], 0, 0, 0);
            acc[1][ct] = __builtin_amdgcn_mfma_f32_16x16x32_bf16(wb, x1, acc[1][ct], 0, 0, 0);
        }
    }

    // ---- epilogue: lane l holds row (l&15), cols (l>>4)*4+{0..3} of tile ----
    const int cbase = (l >> 4) * 4;
#pragma unroll
    for (int rr = 0; rr < 2; rr++) {
        const int grow = blockIdx.x * BM + (rt0 + rr) * 16 + (l & 15);
        if constexpr (!LOGSM) {
            if (grow < M) {
#pragma unroll
                for (int ct = 0; ct < CT; ct++) {
                    f32x4 o = acc[rr][ct];
                    if constexpr (BIAS) {
                        const float4 bv = *(const float4*)&bias[ct * 16 + cbase];
                        o[0] += bv.x; o[1] += bv.y; o[2] += bv.z; o[3] += bv.w;
                    }
                    if constexpr (RELUOUT) {
#pragma unroll
                        for (int j = 0; j < 4; j++) o[j] = fmaxf(o[j], 0.f);
                    }
                    if constexpr (OBF16) {
                        short4v o16;
#pragma unroll
                        for (int j = 0; j < 4; j++) o16[j] = (short)f2bf(o[j]);
                        *(short4v*)&((u16*)outp)[(size_t)grow * NC + ct * 16 + cbase] = o16;
                    } else {
                        *(f32x4*)&((float*)outp)[(size_t)grow * NC + ct * 16 + cbase] = o;
                    }
                }
            }
        } else {
            // fused row log_softmax (row spread across lanes l, l^16, l^32, l^48)
            float v[CT * 4];
#pragma unroll
            for (int ct = 0; ct < CT; ct++) {
                const float4 bv = *(const float4*)&bias[ct * 16 + cbase];
                v[ct * 4 + 0] = acc[rr][ct][0] + bv.x;
                v[ct * 4 + 1] = acc[rr][ct][1] + bv.y;
                v[ct * 4 + 2] = acc[rr][ct][2] + bv.z;
                v[ct * 4 + 3] = acc[rr][ct][3] + bv.w;
            }
            float m = v[0];
#pragma unroll
            for (int j = 1; j < CT * 4; j++) m = fmaxf(m, v[j]);
            m = fmaxf(m, __shfl_xor(m, 16));
            m = fmaxf(m, __shfl_xor(m, 32));
            float s = 0.f;
#pragma unroll
            for (int j = 0; j < CT * 4; j++) s += __expf(v[j] - m);
            s += __shfl_xor(s, 16);
            s += __shfl_xor(s, 32);
            const float lg = m + __logf(s);
            if (grow < M) {
#pragma unroll
                for (int ct = 0; ct < CT; ct++) {
                    f32x4 o;
#pragma unroll
                    for (int j = 0; j < 4; j++) o[j] = v[ct * 4 + j] - lg;
                    *(f32x4*)&((float*)outp)[(size_t)grow * NC + ct * 16 + cbase] = o;
                }
            }
        }
    }
}

// ---------------------------------------------------------------------------
// CSR build: histogram, 3-kernel parallel exclusive scan, bucket fill.
// ---------------------------------------------------------------------------
__global__ __launch_bounds__(256) void hist_k(const int* __restrict__ ei,
                                              int* __restrict__ cnt, int E)
{
    const int gid = blockIdx.x * blockDim.x + threadIdx.x;
    const int stride = gridDim.x * blockDim.x;
    for (int e = gid; e < E; e += stride) atomicAdd(&cnt[ei[E + e]], 1);
}

__global__ __launch_bounds__(256) void bsum_k(const int* __restrict__ cnt,
                                              int* __restrict__ bsum, int N)
{
    __shared__ int ws[4];
    const int i = blockIdx.x * 256 + threadIdx.x;
    int v = (i < N) ? cnt[i] : 0;
    for (int d = 32; d; d >>= 1) v += __shfl_xor(v, d, 64);
    if ((threadIdx.x & 63) == 0) ws[threadIdx.x >> 6] = v;
    __syncthreads();
    if (threadIdx.x == 0) bsum[blockIdx.x] = ws[0] + ws[1] + ws[2] + ws[3];
}

// single block; G1 <= 256
__global__ __launch_bounds__(256) void bscan_k(const int* __restrict__ bsum,
                                               int* __restrict__ bpre, int G1)
{
    __shared__ int part[256];
    const int t = threadIdx.x;
    const int v = (t < G1) ? bsum[t] : 0;
    part[t] = v;
    __syncthreads();
    for (int d = 1; d < 256; d <<= 1) {
        const int u = (t >= d) ? part[t - d] : 0;
        __syncthreads();
        part[t] += u;
        __syncthreads();
    }
    bpre[t] = part[t] - v;   // exclusive
}

__global__ __launch_bounds__(256) void offs_k(const int* __restrict__ cnt,
                                              const int* __restrict__ bpre,
                                              int* __restrict__ off,
                                              int* __restrict__ cursor,
                                              int N, int E)
{
    __shared__ int part[256];
    const int t = threadIdx.x;
    const int i = blockIdx.x * 256 + t;
    const int v = (i < N) ? cnt[i] : 0;
    part[t] = v;
    __syncthreads();
    for (int d = 1; d < 256; d <<= 1) {
        const int u = (t >= d) ? part[t - d] : 0;
        __syncthreads();
        part[t] += u;
        __syncthreads();
    }
    if (i < N) {
        const int o = bpre[blockIdx.x] + part[t] - v;
        off[i] = o;
        cursor[i] = o;
    }
    if (blockIdx.x == 0 && t == 0) off[N] = E;
}

__global__ __launch_bounds__(256) void fill_k(const int* __restrict__ ei,
                                              int* __restrict__ cursor,
                                              int* __restrict__ srcs, int E)
{
    const int gid = blockIdx.x * blockDim.x + threadIdx.x;
    const int stride = gridDim.x * blockDim.x;
    for (int e = gid; e < E; e += stride) {
        const int s = ei[e];
        const int d = ei[E + e];
        const int pos = atomicAdd(&cursor[d], 1);
        srcs[pos] = s;
    }
}

// ---------------------------------------------------------------------------
// Gather segment-sum (bf16 in/out) + fused column stats.
// One wave handles NI=4 nodes INTERLEAVED: per step, 8 index loads (4 nodes
// x 2 edge slots, wave-uniform -> scalar) then 8 independent row gathers,
// then predicated adds. Cross-node independence guarantees ILP ~8.
// C=128 -> lane carries 2 channels (dword); C=64 -> lane = channel (ushort).
// ---------------------------------------------------------------------------
template <int C>
__global__ __launch_bounds__(256) void segsum_bf(
    const u16* __restrict__ p, const int* __restrict__ off,
    const int* __restrict__ srcs, u16* __restrict__ out,
    float* __restrict__ sum, float* __restrict__ sumsq, int N)
{
    constexpr int NI = 4;              // nodes interleaved per wave
    constexpr int VPL = C / 64;        // channels per lane (2 or 1)
    __shared__ float red[4][64][2 * VPL];

    const int wv = threadIdx.x >> 6;
    const int l  = threadIdx.x & 63;
    const int base = (blockIdx.x * 4 + wv) * NI;   // first node of this wave

    float ss[VPL], qq[VPL];
#pragma unroll
    for (int v = 0; v < VPL; v++) { ss[v] = 0.f; qq[v] = 0.f; }

    if (base < N) {
        // one vector load covers off[base .. base+NI] (NI+1 contiguous ints)
        const int ov = off[min(base + min(l, NI), N)];
        int lo[NI], hi[NI], deg[NI];
        int dmax = 0;
#pragma unroll
        for (int i = 0; i < NI; i++) {
            lo[i] = __builtin_amdgcn_readlane(ov, i);
            hi[i] = __builtin_amdgcn_readlane(ov, i + 1);
            deg[i] = (base + i < N) ? (hi[i] - lo[i]) : 0;
            dmax = max(dmax, deg[i]);
        }

        // self rows (4 independent loads)
        float acc[NI][VPL];
#pragma unroll
        for (int i = 0; i < NI; i++) {
            const size_t nn = (size_t)min(base + i, N - 1);
            if constexpr (VPL == 2) {
                const u32 u = *(const u32*)&p[nn * C + 2 * l];
                acc[i][0] = bf2f((u16)u);
                acc[i][1] = bf2f((u16)(u >> 16));
            } else {
                acc[i][0] = bf2f(p[nn * C + l]);
            }
        }

        // interleaved edge loop: 2 steps x 4 nodes per iteration
        for (int j = 0; j < dmax; j += 2) {
            int id[2][NI];
#pragma unroll
            for (int t = 0; t < 2; t++)
#pragma unroll
                for (int i = 0; i < NI; i++) {
                    const int pos = max(min(lo[i] + j + t, hi[i] - 1), 0);
                    id[t][i] = srcs[pos];          // wave-uniform -> s_load
                }
            u32 g[2][NI];
#pragma unroll
            for (int t = 0; t < 2; t++)
#pragma unroll
                for (int i = 0; i < NI; i++) {
                    if constexpr (VPL == 2)
                        g[t][i] = *(const u32*)&p[(size_t)id[t][i] * C + 2 * l];
                    else
                        g[t][i] = p[(size_t)id[t][i] * C + l];
                }
#pragma unroll
            for (int t = 0; t < 2; t++)
#pragma unroll
                for (int i = 0; i < NI; i++) {
                    if (j + t < deg[i]) {          // wave-uniform predicate
                        acc[i][0] += bf2f((u16)g[t][i]);
                        if constexpr (VPL == 2)
                            acc[i][1] += bf2f((u16)(g[t][i] >> 16));
                    }
                }
        }

        // store rounded + stats on rounded values (node order preserved)
#pragma unroll
        for (int i = 0; i < NI; i++) {
            const int n = base + i;
            if (n < N) {
                if constexpr (VPL == 2) {
                    const u16 r0 = f2bf(acc[i][0]);
                    const u16 r1 = f2bf(acc[i][1]);
                    *(u32*)&out[(size_t)n * C + 2 * l] = (u32)r0 | ((u32)r1 << 16);
                    const float f0 = bf2f(r0), f1 = bf2f(r1);
                    ss[0] += f0; qq[0] += f0 * f0;
                    ss[1] += f1; qq[1] += f1 * f1;
                } else {
                    const u16 r = f2bf(acc[i][0]);
                    out[(size_t)n * C + l] = r;
                    const float f = bf2f(r);
                    ss[0] += f; qq[0] += f * f;
                }
            }
        }
    }

    // block reduce across the 4 waves, one atomic per channel per block
#pragma unroll
    for (int v = 0; v < VPL; v++) {
        red[wv][l][2 * v] = ss[v];
        red[wv][l][2 * v + 1] = qq[v];
    }
    __syncthreads();
    if (wv == 0) {
#pragma unroll
        for (int v = 0; v < VPL; v++) {
            float a = 0.f, b = 0.f;
#pragma unroll
            for (int w2 = 0; w2 < 4; w2++) {
                a += red[w2][l][2 * v];
                b += red[w2][l][2 * v + 1];
            }
            const int ch = (VPL == 2) ? (2 * l + v) : l;
            atomAddF(&sum[ch], a);
            atomAddF(&sumsq[ch], b);
        }
    }
}

__global__ void bnfinal_k(const float* __restrict__ sum,
                          const float* __restrict__ sumsq,
                          const float* __restrict__ g,
                          const float* __restrict__ be,
                          float* __restrict__ sc, float* __restrict__ sh,
                          int C, float invN)
{
    const int c = threadIdx.x;
    if (c < C) {
        const float m = sum[c] * invN;
        const float v = sumsq[c] * invN - m * m;
        const float r = rsqrtf(v + 1e-5f);
        const float s = g[c] * r;
        sc[c] = s;
        sh[c] = be[c] - m * s;
    }
}

extern "C" void kernel_launch(void* const* d_in, const int* in_sizes, int n_in,
                              void* d_out, int out_size, void* d_ws, size_t ws_size,
                              hipStream_t stream)
{
    const float* x   = (const float*)d_in[0];
    const int*   ei  = (const int*)d_in[1];
    const float* w1a = (const float*)d_in[2];
    // d_in[3] = b1a: cancelled by BN
    const float* g1  = (const float*)d_in[4];
    const float* be1 = (const float*)d_in[5];
    const float* w1b = (const float*)d_in[6];
    const float* b1b = (const float*)d_in[7];
    const float* w2a = (const float*)d_in[8];
    // d_in[9] = b2a: cancelled by BN
    const float* g2  = (const float*)d_in[10];
    const float* be2 = (const float*)d_in[11];
    const float* w2b = (const float*)d_in[12];
    const float* b2b = (const float*)d_in[13];
    float* out = (float*)d_out;

    const int N = in_sizes[0] / 128;   // 50000
    const int E = in_sizes[1] / 2;     // 800000

    // ---- workspace layout ----
    u16* buf1 = (u16*)d_ws;                      // N*128 bf16 : p1, then h1
    u16* buf2 = buf1 + (size_t)N * 128;          // N*128 bf16 : s1, then p2|s2
    float* stats = (float*)(buf2 + (size_t)N * 128);  // 1024 floats
    float* sum1 = stats,       *sq1 = stats + 128;
    float* sum2 = stats + 256, *sq2 = stats + 320;
    float* sc1  = stats + 384, *sh1 = stats + 512;
    float* sc2  = stats + 640, *sh2 = stats + 704;
    int* cnt    = (int*)(stats + 1024);          // N
    int* off    = cnt + N;                       // N+1
    int* cursor = off + N + 1;                   // N
    int* srcs   = cursor + N;                    // E
    int* bsum   = srcs + E;                      // 256
    int* bpre   = bsum + 256;                    // 256
    short* w1af = (short*)(bpre + 256);          // 128*128
    short* w1bf = w1af + 128 * 128;              // 128*128
    short* w2af = w1bf + 128 * 128;              // 128*64
    short* w2bf = w2af + 128 * 64;               // 64*64
    u16* p1 = buf1;
    u16* s1 = buf2;
    u16* h1 = buf1;                    // reuse: p1 dead after segsum1
    u16* p2 = buf2;                    // reuse: s1 dead after mgemm2 (N*64)
    u16* s2 = buf2 + (size_t)N * 64;   // upper half

    hipMemsetAsync(stats, 0, 1024 * sizeof(float) + (size_t)N * sizeof(int), stream);

    const int G1 = (N + 255) / 256;
    const int gb = (N + 127) / 128;
    const int gs = (N + 15) / 16;      // segsum: 4 waves x 4 nodes per block

    // ---- CSR build ----
    hist_k<<<1024, 256, 0, stream>>>(ei, cnt, E);
    bsum_k<<<G1, 256, 0, stream>>>(cnt, bsum, N);
    bscan_k<<<1, 256, 0, stream>>>(bsum, bpre, G1);
    offs_k<<<G1, 256, 0, stream>>>(cnt, bpre, off, cursor, N, E);
    fill_k<<<1024, 256, 0, stream>>>(ei, cursor, srcs, E);

    // ---- weight prep (one launch for all four) ----
    wprep4_k<<<22, 256, 0, stream>>>(w1a, w1b, w2a, w2b, w1af, w1bf, w2af, w2bf);

    // ---- Layer 1 ----
    mgemm<128, 128, false, false, false, false, false, true>
        <<<gb, 256, 0, stream>>>(x, w1af, nullptr, nullptr, nullptr, p1, N);
    segsum_bf<128><<<gs, 256, 0, stream>>>(p1, off, srcs, s1, sum1, sq1, N);
    bnfinal_k<<<1, 128, 0, stream>>>(sum1, sq1, g1, be1, sc1, sh1, 128, 1.f / N);
    mgemm<128, 128, true, true, true, true, false, true>
        <<<gb, 256, 0, stream>>>(s1, w1bf, sc1, sh1, b1b, h1, N);

    // ---- Layer 2 (aggregate after projecting to 64ch) ----
    mgemm<128, 64, true, false, false, false, false, true>
        <<<gb, 256, 0, stream>>>(h1, w2af, nullptr, nullptr, nullptr, p2, N);
    segsum_bf<64><<<gs, 256, 0, stream>>>(p2, off, srcs, s2, sum2, sq2, N);
    bnfinal_k<<<1, 64, 0, stream>>>(sum2, sq2, g2, be2, sc2, sh2, 64, 1.f / N);
    mgemm<64, 64, true, true, true, false, true, false>
        <<<gb, 256, 0, stream>>>(s2, w2bf, sc2, sh2, b2b, out, N);
}